// Round 1
// baseline (74.931 us; speedup 1.0000x reference)
//
#include <hip/hip_runtime.h>

// ---------------- types / helpers ----------------
using f32x4  = __attribute__((ext_vector_type(4))) float;
using bf16x8 = __attribute__((ext_vector_type(8))) short;

__device__ __forceinline__ unsigned short f2bf(float x) {
  unsigned u = __float_as_uint(x);
  u += 0x7FFFu + ((u >> 16) & 1u);   // round-to-nearest-even
  return (unsigned short)(u >> 16);
}
__device__ __forceinline__ float bf2f(unsigned short v) {
  return __uint_as_float(((unsigned)v) << 16);
}

// Problem constants
// pc1: (8,1024,259)  pc2: (8,4096,131)  W1: (384,256) b1:(256) W2:(256,256) b2:(256)
// out: h (8*4096*256 fp32) then xyz2 (8*4096*3 fp32)
#define OUT_H_ELEMS 8388608

// ---------------- prep: points1 -> bf16 [8][1024][256] ----------------
__global__ void prep_p1(const float* __restrict__ pc1, unsigned short* __restrict__ P1) {
  int tid = blockIdx.x * 256 + threadIdx.x;     // 524288 total
  int r = tid >> 6, l = tid & 63;               // r < 8192 rows, 4 feats/thread
  const float* src = pc1 + (size_t)r * 259 + 3 + l * 4;
  ushort4 v;
  v.x = f2bf(src[0]); v.y = f2bf(src[1]); v.z = f2bf(src[2]); v.w = f2bf(src[3]);
  *(ushort4*)(P1 + ((size_t)r << 8) + l * 4) = v;
}

// ---------------- prep: points2 -> A1 columns [256..384) ----------------
__global__ void prep_p2(const float* __restrict__ pc2, unsigned short* __restrict__ A1) {
  int tid = blockIdx.x * 256 + threadIdx.x;     // 1048576 total
  int r = tid >> 5, l = tid & 31;               // r < 32768 rows, 4 feats/thread
  const float* src = pc2 + (size_t)r * 131 + 3 + l * 4;
  ushort4 v;
  v.x = f2bf(src[0]); v.y = f2bf(src[1]); v.z = f2bf(src[2]); v.w = f2bf(src[3]);
  *(ushort4*)(A1 + (size_t)r * 384 + 256 + l * 4) = v;
}

// ---------------- prep: W1^T, W2^T in bf16 ----------------
__global__ void wconv(const float* __restrict__ W1, const float* __restrict__ W2,
                      unsigned short* __restrict__ W1t, unsigned short* __restrict__ W2t) {
  int id = blockIdx.x * 256 + threadIdx.x;      // 163840 total
  if (id < 98304) {                              // W1t[n][k] = W1[k][n], 256x384
    int n = id / 384, k = id - n * 384;
    W1t[id] = f2bf(W1[k * 256 + n]);
  } else {
    int id2 = id - 98304;                        // W2t[n][k] = W2[k][n], 256x256
    int n = id2 >> 8, k = id2 & 255;
    W2t[id2] = f2bf(W2[k * 256 + n]);
  }
}

// ---------------- 3-NN + weights + xyz2 copy ----------------
#define INSERT(e, j) { \
  bool L2 = ((e) < d2v) || ((e) == d2v && (j) < i2); \
  bool L1 = ((e) < d1 ) || ((e) == d1  && (j) < i1); \
  bool L0 = ((e) < d0 ) || ((e) == d0  && (j) < i0); \
  d2v = L1 ? d1 : (L2 ? (e) : d2v);  i2 = L1 ? i1 : (L2 ? (j) : i2); \
  d1  = L0 ? d0 : (L1 ? (e) : d1 );  i1 = L0 ? i0 : (L1 ? (j) : i1); \
  d0  = L0 ? (e) : d0;               i0 = L0 ? (j) : i0; }

__global__ void nn3_kernel(const float* __restrict__ pc1, const float* __restrict__ pc2,
                           int* __restrict__ idxo, float* __restrict__ wo_,
                           float* __restrict__ xyzo) {
  __shared__ float4 s[1024];
  const int b = blockIdx.x >> 6;
  const int chunk = blockIdx.x & 63;   // 64 points per block
  const int t = threadIdx.x;
  const float* p1b = pc1 + (size_t)b * (1024 * 259);
  #pragma unroll
  for (int j = 0; j < 4; ++j) {
    int r = t + j * 256;
    const float* p = p1b + (size_t)r * 259;
    s[r] = make_float4(p[0], p[1], p[2], 0.f);
  }
  __syncthreads();
  const int n2 = chunk * 64 + (t >> 2);
  const int sub = t & 3;
  const size_t qrow = (size_t)b * 4096 + n2;
  const float* q = pc2 + qrow * 131;
  const float qx = q[0], qy = q[1], qz = q[2];
  float d0 = 3.4e38f, d1 = 3.4e38f, d2v = 3.4e38f;
  int i0 = -1, i1 = -1, i2 = -1;
  #pragma unroll 4
  for (int it = 0; it < 256; ++it) {
    const int c = sub + it * 4;
    float4 p = s[c];
    // match numpy: ((dx*dx + dy*dy) + dz*dz), no FMA contraction
    float dx = __fsub_rn(qx, p.x);
    float dy = __fsub_rn(qy, p.y);
    float dz = __fsub_rn(qz, p.z);
    float d = __fadd_rn(__fadd_rn(__fmul_rn(dx, dx), __fmul_rn(dy, dy)), __fmul_rn(dz, dz));
    bool l2 = d < d2v, l1 = d < d1, l0 = d < d0;   // strict < keeps earlier index on ties
    d2v = l1 ? d1 : (l2 ? d : d2v);  i2 = l1 ? i1 : (l2 ? c : i2);
    d1  = l0 ? d0 : (l1 ? d : d1);   i1 = l0 ? i0 : (l1 ? c : i1);
    d0  = l0 ? d  : d0;              i0 = l0 ? c  : i0;
  }
  // merge top-3 across the 4 lanes of this point (lex order: dist, then index)
  {
    float e0 = __shfl_xor(d0, 1, 64);  int j0 = __shfl_xor(i0, 1, 64);
    float e1 = __shfl_xor(d1, 1, 64);  int j1 = __shfl_xor(i1, 1, 64);
    float e2 = __shfl_xor(d2v, 1, 64); int j2 = __shfl_xor(i2, 1, 64);
    INSERT(e0, j0) INSERT(e1, j1) INSERT(e2, j2)
  }
  {
    float e0 = __shfl_xor(d0, 2, 64);  int j0 = __shfl_xor(i0, 2, 64);
    float e1 = __shfl_xor(d1, 2, 64);  int j1 = __shfl_xor(i1, 2, 64);
    float e2 = __shfl_xor(d2v, 2, 64); int j2 = __shfl_xor(i2, 2, 64);
    INSERT(e0, j0) INSERT(e1, j1) INSERT(e2, j2)
  }
  if (sub == 0) {
    float t0 = fmaxf(d0, 1e-7f), t1 = fmaxf(d1, 1e-7f), t2 = fmaxf(d2v, 1e-7f);
    float r0 = 1.0f / t0, r1 = 1.0f / t1, r2 = 1.0f / t2;
    float nrm = __fadd_rn(__fadd_rn(r0, r1), r2);
    idxo[qrow * 3 + 0] = i0; idxo[qrow * 3 + 1] = i1; idxo[qrow * 3 + 2] = i2;
    wo_[qrow * 3 + 0] = r0 / nrm; wo_[qrow * 3 + 1] = r1 / nrm; wo_[qrow * 3 + 2] = r2 / nrm;
  } else if (sub == 1) {
    xyzo[qrow * 3 + 0] = qx; xyzo[qrow * 3 + 1] = qy; xyzo[qrow * 3 + 2] = qz;
  }
}

// ---------------- interpolation -> A1 columns [0..256) ----------------
__global__ void interp_kernel(const unsigned short* __restrict__ P1, const int* __restrict__ idxb,
                              const float* __restrict__ wb, unsigned short* __restrict__ A1) {
  const int m = blockIdx.x * 4 + (threadIdx.x >> 6);   // one wave per output row
  const int lane = threadIdx.x & 63;
  const int b = m >> 12;
  const int i0 = idxb[m * 3], i1 = idxb[m * 3 + 1], i2 = idxb[m * 3 + 2];
  const float w0 = wb[m * 3], w1 = wb[m * 3 + 1], w2 = wb[m * 3 + 2];
  const unsigned short* base = P1 + ((size_t)b << 18);
  ushort4 g0 = *(const ushort4*)(base + (i0 << 8) + lane * 4);
  ushort4 g1 = *(const ushort4*)(base + (i1 << 8) + lane * 4);
  ushort4 g2 = *(const ushort4*)(base + (i2 << 8) + lane * 4);
  ushort4 ov;
  ov.x = f2bf(fmaf(w2, bf2f(g2.x), fmaf(w1, bf2f(g1.x), w0 * bf2f(g0.x))));
  ov.y = f2bf(fmaf(w2, bf2f(g2.y), fmaf(w1, bf2f(g1.y), w0 * bf2f(g0.y))));
  ov.z = f2bf(fmaf(w2, bf2f(g2.z), fmaf(w1, bf2f(g1.z), w0 * bf2f(g0.z))));
  ov.w = f2bf(fmaf(w2, bf2f(g2.w), fmaf(w1, bf2f(g1.w), w0 * bf2f(g0.w))));
  *(ushort4*)(A1 + (size_t)m * 384 + lane * 4) = ov;
}

// ---------------- bf16 MFMA GEMM: out = relu(A[M,K] * Bt[N,K]^T + bias) ----------------
// 128x128 tile, BK=64, 4 waves (2x2), XOR-swizzled LDS, reg-staged double buffer.
template<int K, bool OUT_BF16>
__global__ __launch_bounds__(256, 2) void gemm_kernel(
    const unsigned short* __restrict__ A, const unsigned short* __restrict__ Bt,
    const float* __restrict__ bias, void* __restrict__ outp) {
  constexpr int NT = K / 64;
  __shared__ char lds[65536];                 // 2 buffers x (16KB A + 16KB B)
  // XCD-chunked bijective swizzle (512 blocks, 8 XCDs)
  int bid = (blockIdx.x & 7) * 64 + (blockIdx.x >> 3);
  const int tn = bid & 1, tm = bid >> 1;      // 2 N-tiles, 256 M-tiles
  const int t = threadIdx.x, lane = t & 63, wv = t >> 6;
  const int wm = wv >> 1, wn = wv & 1;
  const int srow = t >> 3, sslot = t & 7;     // staging: row 0..31 (+j*32), 16B slot 0..7
  const unsigned short* gA = A  + ((size_t)(tm * 128 + srow)) * K + sslot * 8;
  const unsigned short* gB = Bt + ((size_t)(tn * 128 + srow)) * K + sslot * 8;
  int wo[4];
  #pragma unroll
  for (int j = 0; j < 4; ++j) {
    int row = srow + j * 32;
    wo[j] = row * 128 + ((sslot * 16) ^ ((row & 7) << 4));
  }

  f32x4 zero = {0.f, 0.f, 0.f, 0.f};
  f32x4 acc[4][4];
  #pragma unroll
  for (int i = 0; i < 4; ++i)
    #pragma unroll
    for (int j = 0; j < 4; ++j) acc[i][j] = zero;

  f32x4 ra[4], rb[4];
  // prologue: tile 0
  #pragma unroll
  for (int j = 0; j < 4; ++j) {
    ra[j] = *(const f32x4*)(const void*)(gA + j * 32 * K);
    rb[j] = *(const f32x4*)(const void*)(gB + j * 32 * K);
  }
  #pragma unroll
  for (int j = 0; j < 4; ++j) {
    *(f32x4*)(void*)(lds + wo[j]) = ra[j];
    *(f32x4*)(void*)(lds + 16384 + wo[j]) = rb[j];
  }
  __syncthreads();

  int cur = 0;
  #pragma unroll
  for (int kt = 0; kt < NT; ++kt) {
    if (kt + 1 < NT) {
      #pragma unroll
      for (int j = 0; j < 4; ++j) {
        ra[j] = *(const f32x4*)(const void*)(gA + (kt + 1) * 64 + j * 32 * K);
        rb[j] = *(const f32x4*)(const void*)(gB + (kt + 1) * 64 + j * 32 * K);
      }
    }
    char* ab = lds + cur * 32768;
    char* bb = ab + 16384;
    #pragma unroll
    for (int ks = 0; ks < 2; ++ks) {
      bf16x8 af[4], bfr[4];
      const int sl = ks * 4 + (lane >> 4);    // logical 16B k-slot 0..7
      #pragma unroll
      for (int i = 0; i < 4; ++i) {
        int ar = wm * 64 + i * 16 + (lane & 15);
        af[i] = *(const bf16x8*)(void*)(ab + ar * 128 + ((sl * 16) ^ ((ar & 7) << 4)));
        int br = wn * 64 + i * 16 + (lane & 15);
        bfr[i] = *(const bf16x8*)(void*)(bb + br * 128 + ((sl * 16) ^ ((br & 7) << 4)));
      }
      #pragma unroll
      for (int i = 0; i < 4; ++i)
        #pragma unroll
        for (int j = 0; j < 4; ++j)
          acc[i][j] = __builtin_amdgcn_mfma_f32_16x16x32_bf16(af[i], bfr[j], acc[i][j], 0, 0, 0);
    }
    if (kt + 1 < NT) {
      char* wb2 = lds + (cur ^ 1) * 32768;
      #pragma unroll
      for (int j = 0; j < 4; ++j) {
        *(f32x4*)(void*)(wb2 + wo[j]) = ra[j];
        *(f32x4*)(void*)(wb2 + 16384 + wo[j]) = rb[j];
      }
    }
    __syncthreads();
    cur ^= 1;
  }

  // epilogue: C/D layout col=lane&15, row=(lane>>4)*4+reg  [measured m89]
  const int colb = tn * 128 + wn * 64 + (lane & 15);
  const int rowb = tm * 128 + wm * 64 + ((lane >> 4) << 2);
  #pragma unroll
  for (int ni = 0; ni < 4; ++ni) {
    float bv = bias[colb + ni * 16];
    #pragma unroll
    for (int mi = 0; mi < 4; ++mi) {
      #pragma unroll
      for (int r = 0; r < 4; ++r) {
        float v = fmaxf(acc[mi][ni][r] + bv, 0.0f);
        size_t o = (size_t)(rowb + mi * 16 + r) * 256 + (colb + ni * 16);
        if constexpr (OUT_BF16) ((unsigned short*)outp)[o] = f2bf(v);
        else                    ((float*)outp)[o] = v;
      }
    }
  }
}

// ---------------- launch ----------------
extern "C" void kernel_launch(void* const* d_in, const int* in_sizes, int n_in,
                              void* d_out, int out_size, void* d_ws, size_t ws_size,
                              hipStream_t stream) {
  const float* pc1 = (const float*)d_in[0];
  const float* pc2 = (const float*)d_in[1];
  const float* W1  = (const float*)d_in[2];
  const float* b1  = (const float*)d_in[3];
  const float* W2  = (const float*)d_in[4];
  const float* b2  = (const float*)d_in[5];
  float* out = (float*)d_out;
  char* ws = (char*)d_ws;

  int*            idxb = (int*)(ws + 0);                        //  32768*3 int
  float*          wb   = (float*)(ws + 393216);                 //  32768*3 f32
  unsigned short* W1t  = (unsigned short*)(ws + 786432);        //  256x384 bf16
  unsigned short* W2t  = (unsigned short*)(ws + 983040);        //  256x256 bf16
  unsigned short* P1   = (unsigned short*)(ws + 1114112);       //  8x1024x256 bf16
  unsigned short* A1   = (unsigned short*)(ws + 5308416);       //  32768x384 bf16
  unsigned short* H1   = (unsigned short*)(ws + 30474240);      //  32768x256 bf16
  // total ws usage: 47,251,456 bytes

  prep_p1<<<2048, 256, 0, stream>>>(pc1, P1);
  prep_p2<<<4096, 256, 0, stream>>>(pc2, A1);
  wconv<<<640, 256, 0, stream>>>(W1, W2, W1t, W2t);
  nn3_kernel<<<512, 256, 0, stream>>>(pc1, pc2, idxb, wb, out + OUT_H_ELEMS);
  interp_kernel<<<8192, 256, 0, stream>>>(P1, idxb, wb, A1);
  gemm_kernel<384, true ><<<512, 256, 0, stream>>>(A1, W1t, b1, H1);
  gemm_kernel<256, false><<<512, 256, 0, stream>>>(H1, W2t, b2, out);
}

// Round 2
// 69.521 us; speedup vs baseline: 1.0778x; 1.0778x over previous
//
#include <hip/hip_runtime.h>

// ---------------- types / helpers ----------------
using f32x4  = __attribute__((ext_vector_type(4))) float;
using bf16x8 = __attribute__((ext_vector_type(8))) short;

__device__ __forceinline__ unsigned short f2bf(float x) {
  unsigned u = __float_as_uint(x);
  u += 0x7FFFu + ((u >> 16) & 1u);   // round-to-nearest-even
  return (unsigned short)(u >> 16);
}
__device__ __forceinline__ float bf2f(unsigned short v) {
  return __uint_as_float(((unsigned)v) << 16);
}

// pc1: (8,1024,259)  pc2: (8,4096,131)  W1:(384,256) b1:(256) W2:(256,256) b2:(256)
// out: h (8*4096*256 fp32) then xyz2 (8*4096*3 fp32)
#define OUT_H_ELEMS 8388608

// ---------------- fused prep: P1 bf16, A1 cols[256:384), W1^T, W2^T ----------------
__global__ void prep_all(const float* __restrict__ pc1, const float* __restrict__ pc2,
                         const float* __restrict__ W1, const float* __restrict__ W2,
                         unsigned short* __restrict__ P1, unsigned short* __restrict__ A1,
                         unsigned short* __restrict__ W1t, unsigned short* __restrict__ W2t) {
  int tid = blockIdx.x * 256 + threadIdx.x;
  if (tid < 524288) {                       // points1 -> P1 [8192][256] bf16
    int r = tid >> 6, l = tid & 63;
    const float* src = pc1 + (size_t)r * 259 + 3 + l * 4;
    ushort4 v;
    v.x = f2bf(src[0]); v.y = f2bf(src[1]); v.z = f2bf(src[2]); v.w = f2bf(src[3]);
    *(ushort4*)(P1 + ((size_t)r << 8) + l * 4) = v;
  } else if (tid < 1572864) {               // points2 -> A1 cols [256,384)
    int t2 = tid - 524288;
    int r = t2 >> 5, l = t2 & 31;
    const float* src = pc2 + (size_t)r * 131 + 3 + l * 4;
    ushort4 v;
    v.x = f2bf(src[0]); v.y = f2bf(src[1]); v.z = f2bf(src[2]); v.w = f2bf(src[3]);
    *(ushort4*)(A1 + (size_t)r * 384 + 256 + l * 4) = v;
  } else {                                   // weights transpose -> bf16
    int id = tid - 1572864;
    if (id < 98304) {                        // W1t[n][k] = W1[k][n], 256x384
      int n = id / 384, k = id - n * 384;
      W1t[id] = f2bf(W1[k * 256 + n]);
    } else if (id < 163840) {                // W2t[n][k] = W2[k][n], 256x256
      int id2 = id - 98304;
      int n = id2 >> 8, k = id2 & 255;
      W2t[id2] = f2bf(W2[k * 256 + n]);
    }
  }
}

// ---------------- 3-NN + weights + xyz2 copy ----------------
#define INSERT(e, j) { \
  bool L2 = ((e) < d2v) || ((e) == d2v && (j) < i2); \
  bool L1 = ((e) < d1 ) || ((e) == d1  && (j) < i1); \
  bool L0 = ((e) < d0 ) || ((e) == d0  && (j) < i0); \
  d2v = L1 ? d1 : (L2 ? (e) : d2v);  i2 = L1 ? i1 : (L2 ? (j) : i2); \
  d1  = L0 ? d0 : (L1 ? (e) : d1 );  i1 = L0 ? i0 : (L1 ? (j) : i1); \
  d0  = L0 ? (e) : d0;               i0 = L0 ? (j) : i0; }

__global__ void nn3_kernel(const float* __restrict__ pc1, const float* __restrict__ pc2,
                           int* __restrict__ idxo, float* __restrict__ wo_,
                           float* __restrict__ xyzo) {
  __shared__ float4 s[1024];
  const int b = blockIdx.x >> 6;
  const int chunk = blockIdx.x & 63;   // 64 points per block
  const int t = threadIdx.x;
  const float* p1b = pc1 + (size_t)b * (1024 * 259);
  #pragma unroll
  for (int j = 0; j < 4; ++j) {
    int r = t + j * 256;
    const float* p = p1b + (size_t)r * 259;
    s[r] = make_float4(p[0], p[1], p[2], 0.f);
  }
  __syncthreads();
  const int n2 = chunk * 64 + (t >> 2);
  const int sub = t & 3;
  const size_t qrow = (size_t)b * 4096 + n2;
  const float* q = pc2 + qrow * 131;
  const float qx = q[0], qy = q[1], qz = q[2];
  float d0 = 3.4e38f, d1 = 3.4e38f, d2v = 3.4e38f;
  int i0 = -1, i1 = -1, i2 = -1;
  #pragma unroll 4
  for (int it = 0; it < 256; ++it) {
    const int c = sub + it * 4;
    float4 p = s[c];
    // match numpy: ((dx*dx + dy*dy) + dz*dz), no FMA contraction
    float dx = __fsub_rn(qx, p.x);
    float dy = __fsub_rn(qy, p.y);
    float dz = __fsub_rn(qz, p.z);
    float d = __fadd_rn(__fadd_rn(__fmul_rn(dx, dx), __fmul_rn(dy, dy)), __fmul_rn(dz, dz));
    bool l2 = d < d2v, l1 = d < d1, l0 = d < d0;   // strict < keeps earlier index on ties
    d2v = l1 ? d1 : (l2 ? d : d2v);  i2 = l1 ? i1 : (l2 ? c : i2);
    d1  = l0 ? d0 : (l1 ? d : d1);   i1 = l0 ? i0 : (l1 ? c : i1);
    d0  = l0 ? d  : d0;              i0 = l0 ? c  : i0;
  }
  {
    float e0 = __shfl_xor(d0, 1, 64);  int j0 = __shfl_xor(i0, 1, 64);
    float e1 = __shfl_xor(d1, 1, 64);  int j1 = __shfl_xor(i1, 1, 64);
    float e2 = __shfl_xor(d2v, 1, 64); int j2 = __shfl_xor(i2, 1, 64);
    INSERT(e0, j0) INSERT(e1, j1) INSERT(e2, j2)
  }
  {
    float e0 = __shfl_xor(d0, 2, 64);  int j0 = __shfl_xor(i0, 2, 64);
    float e1 = __shfl_xor(d1, 2, 64);  int j1 = __shfl_xor(i1, 2, 64);
    float e2 = __shfl_xor(d2v, 2, 64); int j2 = __shfl_xor(i2, 2, 64);
    INSERT(e0, j0) INSERT(e1, j1) INSERT(e2, j2)
  }
  if (sub == 0) {
    float t0 = fmaxf(d0, 1e-7f), t1 = fmaxf(d1, 1e-7f), t2 = fmaxf(d2v, 1e-7f);
    float r0 = 1.0f / t0, r1 = 1.0f / t1, r2 = 1.0f / t2;
    float nrm = __fadd_rn(__fadd_rn(r0, r1), r2);
    idxo[qrow * 3 + 0] = i0; idxo[qrow * 3 + 1] = i1; idxo[qrow * 3 + 2] = i2;
    wo_[qrow * 3 + 0] = r0 / nrm; wo_[qrow * 3 + 1] = r1 / nrm; wo_[qrow * 3 + 2] = r2 / nrm;
  } else if (sub == 1) {
    xyzo[qrow * 3 + 0] = qx; xyzo[qrow * 3 + 1] = qy; xyzo[qrow * 3 + 2] = qz;
  }
}

// ---------------- interpolation -> A1 columns [0..256) ----------------
__global__ void interp_kernel(const unsigned short* __restrict__ P1, const int* __restrict__ idxb,
                              const float* __restrict__ wb, unsigned short* __restrict__ A1) {
  const int m = blockIdx.x * 4 + (threadIdx.x >> 6);   // one wave per output row
  const int lane = threadIdx.x & 63;
  const int b = m >> 12;
  const int i0 = idxb[m * 3], i1 = idxb[m * 3 + 1], i2 = idxb[m * 3 + 2];
  const float w0 = wb[m * 3], w1 = wb[m * 3 + 1], w2 = wb[m * 3 + 2];
  const unsigned short* base = P1 + ((size_t)b << 18);
  ushort4 g0 = *(const ushort4*)(base + (i0 << 8) + lane * 4);
  ushort4 g1 = *(const ushort4*)(base + (i1 << 8) + lane * 4);
  ushort4 g2 = *(const ushort4*)(base + (i2 << 8) + lane * 4);
  ushort4 ov;
  ov.x = f2bf(fmaf(w2, bf2f(g2.x), fmaf(w1, bf2f(g1.x), w0 * bf2f(g0.x))));
  ov.y = f2bf(fmaf(w2, bf2f(g2.y), fmaf(w1, bf2f(g1.y), w0 * bf2f(g0.y))));
  ov.z = f2bf(fmaf(w2, bf2f(g2.z), fmaf(w1, bf2f(g1.z), w0 * bf2f(g0.z))));
  ov.w = f2bf(fmaf(w2, bf2f(g2.w), fmaf(w1, bf2f(g1.w), w0 * bf2f(g0.w))));
  *(ushort4*)(A1 + (size_t)m * 384 + lane * 4) = ov;
}

// ---------------- fused two-layer MFMA GEMM ----------------
// Block: 512 threads (8 waves, 2x4), 128 rows, full N=256. 160KB dynamic LDS.
// Phase 1: H = relu(A1[128][384] @ W1t^T + b1) -> LDS bf16 (swizzled, never HBM)
// Phase 2: out = relu(H @ W2t^T + b2) -> LDS f32 transpose -> coalesced store
__global__ __launch_bounds__(512, 2) void fused_gemm(
    const unsigned short* __restrict__ A1, const unsigned short* __restrict__ W1t,
    const unsigned short* __restrict__ W2t, const float* __restrict__ b1,
    const float* __restrict__ b2, float* __restrict__ out) {
  extern __shared__ char lds[];
  char* Hbuf = lds;                       // [0, 64K): H tile 128x256 bf16, row stride 512B
  char* Bb[2] = { lds + 65536, lds + 98304 };    // 32KB each: B / W2 stage
  char* Ab[2] = { lds + 131072, lds + 147456 };  // 16KB each: A stage

  const int t = threadIdx.x, lane = t & 63, wv = t >> 6;
  const int wm = wv >> 2, wn = wv & 3;    // 2 x 4 wave grid, each 64x64 output
  const int m0 = blockIdx.x * 128;

  // staging assignment: A-tile 128x64 bf16 (1024 16B-slots, 2/thread);
  //                     B-tile 256x64 bf16 (2048 slots, 4/thread)
  const int arow = t >> 2, as0 = (t & 3) * 2;
  const int brow = t >> 1, bs0 = (t & 1) * 4;
  const unsigned short* gA  = A1  + (size_t)(m0 + arow) * 384 + as0 * 8;
  const unsigned short* gB1 = W1t + (size_t)brow * 384 + bs0 * 8;
  const unsigned short* gW2 = W2t + (size_t)brow * 256 + bs0 * 8;
  int awo[2], bwo[4];
  #pragma unroll
  for (int j = 0; j < 2; ++j)
    awo[j] = arow * 128 + (((as0 + j) * 16) ^ ((arow & 7) << 4));
  #pragma unroll
  for (int j = 0; j < 4; ++j)
    bwo[j] = brow * 128 + (((bs0 + j) * 16) ^ ((brow & 7) << 4));

  f32x4 zero = {0.f, 0.f, 0.f, 0.f};
  f32x4 acc[4][4];
  #pragma unroll
  for (int i = 0; i < 4; ++i)
    #pragma unroll
    for (int j = 0; j < 4; ++j) acc[i][j] = zero;

  f32x4 ra[2], rb[4];
  // ---- phase 1: 6 k-tiles of 64 ----
  #pragma unroll
  for (int j = 0; j < 2; ++j) ra[j] = *(const f32x4*)(const void*)(gA + j * 8);
  #pragma unroll
  for (int j = 0; j < 4; ++j) rb[j] = *(const f32x4*)(const void*)(gB1 + j * 8);
  #pragma unroll
  for (int j = 0; j < 2; ++j) *(f32x4*)(void*)(Ab[0] + awo[j]) = ra[j];
  #pragma unroll
  for (int j = 0; j < 4; ++j) *(f32x4*)(void*)(Bb[0] + bwo[j]) = rb[j];
  __syncthreads();

  int cur = 0;
  #pragma unroll
  for (int kt = 0; kt < 6; ++kt) {
    if (kt < 5) {
      #pragma unroll
      for (int j = 0; j < 2; ++j) ra[j] = *(const f32x4*)(const void*)(gA + (kt + 1) * 64 + j * 8);
      #pragma unroll
      for (int j = 0; j < 4; ++j) rb[j] = *(const f32x4*)(const void*)(gB1 + (kt + 1) * 64 + j * 8);
    }
    #pragma unroll
    for (int ks = 0; ks < 2; ++ks) {
      bf16x8 af[4], bfr[4];
      const int sl = ks * 4 + (lane >> 4);
      #pragma unroll
      for (int i = 0; i < 4; ++i) {
        int ar = wm * 64 + i * 16 + (lane & 15);
        af[i] = *(const bf16x8*)(void*)(Ab[cur] + ar * 128 + ((sl * 16) ^ ((ar & 7) << 4)));
        int br = wn * 64 + i * 16 + (lane & 15);
        bfr[i] = *(const bf16x8*)(void*)(Bb[cur] + br * 128 + ((sl * 16) ^ ((br & 7) << 4)));
      }
      #pragma unroll
      for (int i = 0; i < 4; ++i)
        #pragma unroll
        for (int j = 0; j < 4; ++j)
          acc[i][j] = __builtin_amdgcn_mfma_f32_16x16x32_bf16(af[i], bfr[j], acc[i][j], 0, 0, 0);
    }
    if (kt < 5) {
      #pragma unroll
      for (int j = 0; j < 2; ++j) *(f32x4*)(void*)(Ab[cur ^ 1] + awo[j]) = ra[j];
      #pragma unroll
      for (int j = 0; j < 4; ++j) *(f32x4*)(void*)(Bb[cur ^ 1] + bwo[j]) = rb[j];
    }
    __syncthreads();
    cur ^= 1;
  }

  // ---- phase-1 epilogue: relu+bias -> bf16 -> Hbuf (swizzled) ----
  const int colb = wn * 64 + (lane & 15);
  const int rowb = wm * 64 + ((lane >> 4) << 2);
  #pragma unroll
  for (int ni = 0; ni < 4; ++ni) {
    float bv = b1[colb + ni * 16];
    #pragma unroll
    for (int mi = 0; mi < 4; ++mi) {
      #pragma unroll
      for (int r = 0; r < 4; ++r) {
        float v = fmaxf(acc[mi][ni][r] + bv, 0.0f);
        int row = rowb + mi * 16 + r, col = colb + ni * 16;
        *(unsigned short*)(Hbuf + row * 512 + ((col * 2) ^ ((row & 15) << 4))) = f2bf(v);
        acc[mi][ni][r] = 0.0f;   // reinit for phase 2
      }
    }
  }
  // stage W2 k-tile 0 into Bb[0]
  #pragma unroll
  for (int j = 0; j < 4; ++j) rb[j] = *(const f32x4*)(const void*)(gW2 + j * 8);
  #pragma unroll
  for (int j = 0; j < 4; ++j) *(f32x4*)(void*)(Bb[0] + bwo[j]) = rb[j];
  __syncthreads();

  // ---- phase 2: 4 k-tiles of 64, A = Hbuf (LDS-resident) ----
  cur = 0;
  #pragma unroll
  for (int kt = 0; kt < 4; ++kt) {
    if (kt < 3) {
      #pragma unroll
      for (int j = 0; j < 4; ++j) rb[j] = *(const f32x4*)(const void*)(gW2 + (kt + 1) * 64 + j * 8);
    }
    #pragma unroll
    for (int ks = 0; ks < 2; ++ks) {
      bf16x8 af[4], bfr[4];
      const int sl = ks * 4 + (lane >> 4);
      #pragma unroll
      for (int i = 0; i < 4; ++i) {
        int hr = wm * 64 + i * 16 + (lane & 15);
        af[i] = *(const bf16x8*)(void*)(Hbuf + hr * 512 + ((kt * 128 + sl * 16) ^ ((hr & 15) << 4)));
        int wr = wn * 64 + i * 16 + (lane & 15);
        bfr[i] = *(const bf16x8*)(void*)(Bb[cur] + wr * 128 + ((sl * 16) ^ ((wr & 7) << 4)));
      }
      #pragma unroll
      for (int i = 0; i < 4; ++i)
        #pragma unroll
        for (int j = 0; j < 4; ++j)
          acc[i][j] = __builtin_amdgcn_mfma_f32_16x16x32_bf16(af[i], bfr[j], acc[i][j], 0, 0, 0);
    }
    if (kt < 3) {
      #pragma unroll
      for (int j = 0; j < 4; ++j) *(f32x4*)(void*)(Bb[cur ^ 1] + bwo[j]) = rb[j];
    }
    __syncthreads();
    cur ^= 1;
  }

  // ---- phase-2 epilogue: relu+bias -> f32 LDS transpose -> coalesced store ----
  #pragma unroll
  for (int ni = 0; ni < 4; ++ni) {
    float bv = b2[colb + ni * 16];
    #pragma unroll
    for (int mi = 0; mi < 4; ++mi) {
      #pragma unroll
      for (int r = 0; r < 4; ++r) {
        float v = fmaxf(acc[mi][ni][r] + bv, 0.0f);
        int row = rowb + mi * 16 + r, col = colb + ni * 16;
        *(float*)(lds + row * 1024 + ((col * 4) ^ ((row & 15) << 4))) = v;
      }
    }
  }
  __syncthreads();
  #pragma unroll
  for (int q = 0; q < 16; ++q) {
    int row = q * 8 + wv;
    f32x4 v = *(const f32x4*)(void*)(lds + row * 1024 + ((lane * 16) ^ ((row & 15) << 4)));
    *(f32x4*)(out + (size_t)(m0 + row) * 256 + lane * 4) = v;   // full 1KB row per wave op
  }
}

// ---------------- launch ----------------
extern "C" void kernel_launch(void* const* d_in, const int* in_sizes, int n_in,
                              void* d_out, int out_size, void* d_ws, size_t ws_size,
                              hipStream_t stream) {
  const float* pc1 = (const float*)d_in[0];
  const float* pc2 = (const float*)d_in[1];
  const float* W1  = (const float*)d_in[2];
  const float* b1  = (const float*)d_in[3];
  const float* W2  = (const float*)d_in[4];
  const float* b2  = (const float*)d_in[5];
  float* out = (float*)d_out;
  char* ws = (char*)d_ws;

  int*            idxb = (int*)(ws + 0);                        // 32768*3 int
  float*          wb   = (float*)(ws + 393216);                 // 32768*3 f32
  unsigned short* W1t  = (unsigned short*)(ws + 786432);        // 256x384 bf16
  unsigned short* W2t  = (unsigned short*)(ws + 983040);        // 256x256 bf16
  unsigned short* P1   = (unsigned short*)(ws + 1114112);       // 8x1024x256 bf16
  unsigned short* A1   = (unsigned short*)(ws + 5308416);       // 32768x384 bf16
  // ws usage ends at 30,474,240 bytes

  static int lds_set = 0;
  hipFuncSetAttribute((const void*)fused_gemm, hipFuncAttributeMaxDynamicSharedMemorySize, 163840);
  (void)lds_set;

  prep_all<<<6784, 256, 0, stream>>>(pc1, pc2, W1, W2, P1, A1, W1t, W2t);
  nn3_kernel<<<512, 256, 0, stream>>>(pc1, pc2, idxb, wb, out + OUT_H_ELEMS);
  interp_kernel<<<8192, 256, 0, stream>>>(P1, idxb, wb, A1);
  fused_gemm<<<256, 512, 163840, stream>>>(A1, W1t, W2t, b1, b2, out);
}